// Round 2
// baseline (1740.605 us; speedup 1.0000x reference)
//
#include <hip/hip_runtime.h>
#include <hip/hip_bf16.h>

// Split architecture:
//  kernel 1 (encode): level-major grid. All CUs process the SAME hash level at
//    a time, so each XCD's 4 MiB L2 holds that level's 4 MiB table -> gather
//    fetch drops from ~4.8 GB to ~compulsory. Output h stored feature-major
//    [32][N] so stores (and the MLP's loads) are fully coalesced.
//  kernel 2 (MLP): one thread per point, fully unrolled, all activations in
//    registers (compile-time indexing), weights broadcast from 28 KB LDS.
// Fallback: if ws_size < 32*N floats, run the old fused kernel (correct, slower).

#define NLVL 16
#define TSZ   524288u          // hash table entries per level (2^19)
#define TMASK 524287u
#define PR1 2654435761u
#define PR2 805459861u

// floor(16 * 1.5^l)
__device__ __constant__ int kResC[NLVL] = {16,24,36,54,81,121,182,273,410,615,922,1383,2075,3113,4670,7006};
constexpr int kRes[NLVL] = {16,24,36,54,81,121,182,273,410,615,922,1383,2075,3113,4670,7006};
constexpr bool kDense[NLVL] = {true,true,true,true,false,false,false,false,
                               false,false,false,false,false,false,false,false};

// ---------------- encode helpers ----------------

__device__ __forceinline__ void trilerp(const float2 f0, const float2 f1, const float2 f2, const float2 f3,
                                        const float2 f4, const float2 f5, const float2 f6, const float2 f7,
                                        float wx, float wy, float wz, float& a0, float& a1)
{
    const float ax = 1.f - wx, ay = 1.f - wy, az = 1.f - wz;
    const float g00 = ax * ay, g01 = ax * wy, g10 = wx * ay, g11 = wx * wy;
    float s0 = 0.f, s1 = 0.f, v;
    v = g00 * az; s0 = fmaf(v, f0.x, s0); s1 = fmaf(v, f0.y, s1);
    v = g00 * wz; s0 = fmaf(v, f1.x, s0); s1 = fmaf(v, f1.y, s1);
    v = g01 * az; s0 = fmaf(v, f2.x, s0); s1 = fmaf(v, f2.y, s1);
    v = g01 * wz; s0 = fmaf(v, f3.x, s0); s1 = fmaf(v, f3.y, s1);
    v = g10 * az; s0 = fmaf(v, f4.x, s0); s1 = fmaf(v, f4.y, s1);
    v = g10 * wz; s0 = fmaf(v, f5.x, s0); s1 = fmaf(v, f5.y, s1);
    v = g11 * az; s0 = fmaf(v, f6.x, s0); s1 = fmaf(v, f6.y, s1);
    v = g11 * wz; s0 = fmaf(v, f7.x, s0); s1 = fmaf(v, f7.y, s1);
    a0 = s0; a1 = s1;
}

__device__ __forceinline__ void hash_point(float px, float py, float pz, float res,
                                           const float2* __restrict__ tl,
                                           float& a0, float& a1)
{
    const float fx = px * res, fy = py * res, fz = pz * res;
    const float bx = floorf(fx), by = floorf(fy), bz = floorf(fz);
    const float wx = fx - bx, wy = fy - by, wz = fz - bz;
    const unsigned cx = (unsigned)bx, cy = (unsigned)by, cz = (unsigned)bz;
    const unsigned hy0 = cy * PR1, hy1 = hy0 + PR1;
    const unsigned hz0 = cz * PR2, hz1 = hz0 + PR2;
    const unsigned e00 = hy0 ^ hz0, e01 = hy0 ^ hz1, e10 = hy1 ^ hz0, e11 = hy1 ^ hz1;
    const unsigned x1 = cx + 1u;
    const float2 f0 = tl[(cx ^ e00) & TMASK];
    const float2 f1 = tl[(cx ^ e01) & TMASK];
    const float2 f2 = tl[(cx ^ e10) & TMASK];
    const float2 f3 = tl[(cx ^ e11) & TMASK];
    const float2 f4 = tl[(x1 ^ e00) & TMASK];
    const float2 f5 = tl[(x1 ^ e01) & TMASK];
    const float2 f6 = tl[(x1 ^ e10) & TMASK];
    const float2 f7 = tl[(x1 ^ e11) & TMASK];
    trilerp(f0,f1,f2,f3,f4,f5,f6,f7, wx,wy,wz, a0,a1);
}

template<int RES>
__device__ __forceinline__ void dense_point(float px, float py, float pz,
                                            const float2* __restrict__ tl,
                                            float& a0, float& a1)
{
    const float res = (float)RES;
    const float fx = px * res, fy = py * res, fz = pz * res;
    const float bx = floorf(fx), by = floorf(fy), bz = floorf(fz);
    const float wx = fx - bx, wy = fy - by, wz = fz - bz;
    const unsigned cx = (unsigned)bx, cy = (unsigned)by, cz = (unsigned)bz;
    const unsigned s = RES + 1u, s2 = s * s;
    const unsigned b = cx + cy * s + cz * s2;
    const float2 f0 = tl[b];
    const float2 f1 = tl[b + s2];
    const float2 f2 = tl[b + s];
    const float2 f3 = tl[b + s + s2];
    const float2 f4 = tl[b + 1u];
    const float2 f5 = tl[b + 1u + s2];
    const float2 f6 = tl[b + 1u + s];
    const float2 f7 = tl[b + 1u + s + s2];
    trilerp(f0,f1,f2,f3,f4,f5,f6,f7, wx,wy,wz, a0,a1);
}

// grid = 13 passes * 4096 blocks; pass 0 = dense levels 0..3, pass p>=1 = hashed level p+3.
// 512 points per block (2 per thread). Level-major blockIdx order keeps all CUs
// on the same 4 MiB table concurrently -> per-XCD L2 retains it.
__global__ __launch_bounds__(256)
void encode_kernel(const float* __restrict__ x, const float* __restrict__ table,
                   float* __restrict__ hT, int n)
{
    const int bid = blockIdx.x;
    const int pass = bid >> 12;
    const int chunk = bid & 4095;
    const int t = threadIdx.x;
    const int base = chunk * 512 + t;

    if (pass == 0) {
#pragma unroll
        for (int p = 0; p < 2; ++p) {
            const int i = base + p * 256;
            if (i >= n) continue;
            const float px = x[3*i+0], py = x[3*i+1], pz = x[3*i+2];
            float a0, a1;
            dense_point<16>(px,py,pz, (const float2*)table + (size_t)0*TSZ, a0,a1);
            hT[(size_t)0*n + i] = a0; hT[(size_t)1*n + i] = a1;
            dense_point<24>(px,py,pz, (const float2*)table + (size_t)1*TSZ, a0,a1);
            hT[(size_t)2*n + i] = a0; hT[(size_t)3*n + i] = a1;
            dense_point<36>(px,py,pz, (const float2*)table + (size_t)2*TSZ, a0,a1);
            hT[(size_t)4*n + i] = a0; hT[(size_t)5*n + i] = a1;
            dense_point<54>(px,py,pz, (const float2*)table + (size_t)3*TSZ, a0,a1);
            hT[(size_t)6*n + i] = a0; hT[(size_t)7*n + i] = a1;
        }
    } else {
        const int l = pass + 3;                       // 4..15, uniform
        const float res = (float)kResC[l];            // scalar load
        const float2* tl = (const float2*)table + (size_t)l * TSZ;
        float* __restrict__ r0 = hT + (size_t)(2*l) * n;
        float* __restrict__ r1 = r0 + n;
#pragma unroll
        for (int p = 0; p < 2; ++p) {
            const int i = base + p * 256;
            if (i >= n) continue;
            const float px = x[3*i+0], py = x[3*i+1], pz = x[3*i+2];
            float a0, a1;
            hash_point(px,py,pz, res, tl, a0,a1);
            r0[i] = a0; r1[i] = a1;
        }
    }
}

// ---------------- MLP kernel: fully register-resident ----------------

__global__ __launch_bounds__(256)
void mlp_kernel(const float* __restrict__ hT,
                const float* __restrict__ W1,
                const float* __restrict__ W2,
                const float* __restrict__ W3,
                float* __restrict__ out, int n)
{
    __shared__ float sW1[32 * 64];   //  8 KB
    __shared__ float sW2[64 * 64];   // 16 KB
    __shared__ float sW3[64 * 16];   //  4 KB
    const int t = threadIdx.x;
#pragma unroll
    for (int r = 0; r < 8; ++r)  sW1[r * 256 + t] = W1[r * 256 + t];
#pragma unroll
    for (int r = 0; r < 16; ++r) sW2[r * 256 + t] = W2[r * 256 + t];
#pragma unroll
    for (int r = 0; r < 4; ++r)  sW3[r * 256 + t] = W3[r * 256 + t];
    __syncthreads();

    const int i = blockIdx.x * 256 + t;
    if (i >= n) return;

    // h: 32 coalesced loads from feature-major hT
    float h[32];
#pragma unroll
    for (int f = 0; f < 32; ++f) h[f] = hT[(size_t)f * n + i];

    // layer 1: h[32] @ W1[32,64] -> relu(h1[64])
    float h1[64];
#pragma unroll
    for (int j = 0; j < 64; ++j) h1[j] = 0.f;
#pragma unroll
    for (int k = 0; k < 32; ++k) {
        const float hk = h[k];
        const float4* __restrict__ wr = reinterpret_cast<const float4*>(&sW1[k * 64]);
#pragma unroll
        for (int q = 0; q < 16; ++q) {
            const float4 wv = wr[q];
            h1[4*q+0] = fmaf(hk, wv.x, h1[4*q+0]);
            h1[4*q+1] = fmaf(hk, wv.y, h1[4*q+1]);
            h1[4*q+2] = fmaf(hk, wv.z, h1[4*q+2]);
            h1[4*q+3] = fmaf(hk, wv.w, h1[4*q+3]);
        }
    }
#pragma unroll
    for (int j = 0; j < 64; ++j) h1[j] = fmaxf(h1[j], 0.f);

    // layers 2+3 fused in two 32-wide halves to cap live registers:
    //   h2half = relu(h1 @ W2[:, half]);  h3 += h2half @ W3[half, :]
    float h3[16];
#pragma unroll
    for (int j = 0; j < 16; ++j) h3[j] = 0.f;

#pragma unroll
    for (int half = 0; half < 2; ++half) {
        float h2[32];
#pragma unroll
        for (int j = 0; j < 32; ++j) h2[j] = 0.f;
#pragma unroll
        for (int k = 0; k < 64; ++k) {
            const float hk = h1[k];
            const float4* __restrict__ wr = reinterpret_cast<const float4*>(&sW2[k * 64 + half * 32]);
#pragma unroll
            for (int q = 0; q < 8; ++q) {
                const float4 wv = wr[q];
                h2[4*q+0] = fmaf(hk, wv.x, h2[4*q+0]);
                h2[4*q+1] = fmaf(hk, wv.y, h2[4*q+1]);
                h2[4*q+2] = fmaf(hk, wv.z, h2[4*q+2]);
                h2[4*q+3] = fmaf(hk, wv.w, h2[4*q+3]);
            }
        }
#pragma unroll
        for (int j = 0; j < 32; ++j) h2[j] = fmaxf(h2[j], 0.f);
#pragma unroll
        for (int k = 0; k < 32; ++k) {
            const float hk = h2[k];
            const float4* __restrict__ wr = reinterpret_cast<const float4*>(&sW3[(half * 32 + k) * 16]);
#pragma unroll
            for (int q = 0; q < 4; ++q) {
                const float4 wv = wr[q];
                h3[4*q+0] = fmaf(hk, wv.x, h3[4*q+0]);
                h3[4*q+1] = fmaf(hk, wv.y, h3[4*q+1]);
                h3[4*q+2] = fmaf(hk, wv.z, h3[4*q+2]);
                h3[4*q+3] = fmaf(hk, wv.w, h3[4*q+3]);
            }
        }
    }

    float4* __restrict__ o = reinterpret_cast<float4*>(out + (size_t)i * 16);
    o[0] = make_float4(h3[0],  h3[1],  h3[2],  h3[3]);
    o[1] = make_float4(h3[4],  h3[5],  h3[6],  h3[7]);
    o[2] = make_float4(h3[8],  h3[9],  h3[10], h3[11]);
    o[3] = make_float4(h3[12], h3[13], h3[14], h3[15]);
}

// ---------------- fallback: previous fused kernel (known-correct) ----------------

__global__ __launch_bounds__(256)
void ngp_fused_kernel(const float* __restrict__ x,
                      const float* __restrict__ table,
                      const float* __restrict__ W1,
                      const float* __restrict__ W2,
                      const float* __restrict__ W3,
                      float* __restrict__ out,
                      int n)
{
    __shared__ float sW1[32 * 64];
    __shared__ float sW2[64 * 64];
    __shared__ float sW3[64 * 16];
    __shared__ float hS[32 * 256];

    const int t = threadIdx.x;
#pragma unroll
    for (int r = 0; r < 8; ++r)  sW1[r * 256 + t] = W1[r * 256 + t];
#pragma unroll
    for (int r = 0; r < 16; ++r) sW2[r * 256 + t] = W2[r * 256 + t];
#pragma unroll
    for (int r = 0; r < 4; ++r)  sW3[r * 256 + t] = W3[r * 256 + t];
    __syncthreads();

    const int i = blockIdx.x * 256 + t;
    if (i >= n) return;

    const float px = x[3*i+0], py = x[3*i+1], pz = x[3*i+2];

    float h[32];
#pragma unroll
    for (int l = 0; l < NLVL; ++l) {
        float a0, a1;
        if (kDense[l]) {
            const int r = kRes[l];
            if (r == 16) dense_point<16>(px,py,pz,(const float2*)table+(size_t)l*TSZ,a0,a1);
            else if (r == 24) dense_point<24>(px,py,pz,(const float2*)table+(size_t)l*TSZ,a0,a1);
            else if (r == 36) dense_point<36>(px,py,pz,(const float2*)table+(size_t)l*TSZ,a0,a1);
            else dense_point<54>(px,py,pz,(const float2*)table+(size_t)l*TSZ,a0,a1);
        } else {
            hash_point(px,py,pz,(float)kRes[l],(const float2*)table+(size_t)l*TSZ,a0,a1);
        }
        h[2*l+0] = a0; h[2*l+1] = a1;
    }

#pragma unroll
    for (int k = 0; k < 32; ++k) hS[k * 256 + t] = h[k];

    float h1[64];
#pragma unroll
    for (int j = 0; j < 64; ++j) h1[j] = 0.f;
    for (int k = 0; k < 32; ++k) {
        const float hk = hS[k * 256 + t];
        const float4* __restrict__ wr = reinterpret_cast<const float4*>(&sW1[k * 64]);
#pragma unroll
        for (int q = 0; q < 16; ++q) {
            const float4 wv = wr[q];
            h1[4*q+0] = fmaf(hk, wv.x, h1[4*q+0]);
            h1[4*q+1] = fmaf(hk, wv.y, h1[4*q+1]);
            h1[4*q+2] = fmaf(hk, wv.z, h1[4*q+2]);
            h1[4*q+3] = fmaf(hk, wv.w, h1[4*q+3]);
        }
    }
#pragma unroll
    for (int j = 0; j < 64; ++j) h1[j] = fmaxf(h1[j], 0.f);

    float h2[64];
#pragma unroll
    for (int j = 0; j < 64; ++j) h2[j] = 0.f;
#pragma unroll
    for (int half = 0; half < 2; ++half) {
#pragma unroll
        for (int k = 0; k < 32; ++k) hS[k * 256 + t] = h1[half * 32 + k];
        for (int k = 0; k < 32; ++k) {
            const float hk = hS[k * 256 + t];
            const float4* __restrict__ wr = reinterpret_cast<const float4*>(&sW2[(half * 32 + k) * 64]);
#pragma unroll
            for (int q = 0; q < 16; ++q) {
                const float4 wv = wr[q];
                h2[4*q+0] = fmaf(hk, wv.x, h2[4*q+0]);
                h2[4*q+1] = fmaf(hk, wv.y, h2[4*q+1]);
                h2[4*q+2] = fmaf(hk, wv.z, h2[4*q+2]);
                h2[4*q+3] = fmaf(hk, wv.w, h2[4*q+3]);
            }
        }
    }
#pragma unroll
    for (int j = 0; j < 64; ++j) h2[j] = fmaxf(h2[j], 0.f);

    float h3[16];
#pragma unroll
    for (int j = 0; j < 16; ++j) h3[j] = 0.f;
#pragma unroll
    for (int half = 0; half < 2; ++half) {
#pragma unroll
        for (int k = 0; k < 32; ++k) hS[k * 256 + t] = h2[half * 32 + k];
        for (int k = 0; k < 32; ++k) {
            const float hk = hS[k * 256 + t];
            const float4* __restrict__ wr = reinterpret_cast<const float4*>(&sW3[(half * 32 + k) * 16]);
#pragma unroll
            for (int q = 0; q < 4; ++q) {
                const float4 wv = wr[q];
                h3[4*q+0] = fmaf(hk, wv.x, h3[4*q+0]);
                h3[4*q+1] = fmaf(hk, wv.y, h3[4*q+1]);
                h3[4*q+2] = fmaf(hk, wv.z, h3[4*q+2]);
                h3[4*q+3] = fmaf(hk, wv.w, h3[4*q+3]);
            }
        }
    }

    float4* __restrict__ o = reinterpret_cast<float4*>(out + (size_t)i * 16);
    o[0] = make_float4(h3[0],  h3[1],  h3[2],  h3[3]);
    o[1] = make_float4(h3[4],  h3[5],  h3[6],  h3[7]);
    o[2] = make_float4(h3[8],  h3[9],  h3[10], h3[11]);
    o[3] = make_float4(h3[12], h3[13], h3[14], h3[15]);
}

extern "C" void kernel_launch(void* const* d_in, const int* in_sizes, int n_in,
                              void* d_out, int out_size, void* d_ws, size_t ws_size,
                              hipStream_t stream) {
    const float* x     = (const float*)d_in[0];
    const float* table = (const float*)d_in[1];
    const float* W1    = (const float*)d_in[2];
    const float* W2    = (const float*)d_in[3];
    const float* W3    = (const float*)d_in[4];
    float* out = (float*)d_out;

    const int n = in_sizes[0] / 3;
    const size_t need = (size_t)n * 32 * sizeof(float);

    if (ws_size >= need) {
        float* hT = (float*)d_ws;                       // [32][n] feature-major
        const int chunks = (n + 511) / 512;             // points per block = 512
        // level-major grid: pass 0 = dense levels, passes 1..12 = hashed levels
        // (chunks is 4096 for n = 2^21; encode_kernel assumes 4096-block passes)
        encode_kernel<<<13 * 4096, 256, 0, stream>>>(x, table, hT, n);
        (void)chunks;
        mlp_kernel<<<(n + 255) / 256, 256, 0, stream>>>(hT, W1, W2, W3, out, n);
    } else {
        ngp_fused_kernel<<<(n + 255) / 256, 256, 0, stream>>>(x, table, W1, W2, W3, out, n);
    }
}

// Round 9
// 1573.348 us; speedup vs baseline: 1.1063x; 1.1063x over previous
//
#include <hip/hip_runtime.h>
#include <hip/hip_bf16.h>

// R3 (resubmit x6 — infra failures, never measured): three-kernel split.
//  encode_dense: levels 0-3 (small tables, L1/L2-resident), 1 pt/thread.
//  encode_hash : levels 4-15, level-major grid (per-XCD L2 keeps the 4 MiB
//    table), 4 pts/thread with all 32 gathers in flight before consumption
//    (tests the per-CU miss-concurrency limit).
//  mlp_kernel  : weights read via wave-uniform global loads (compiler
//    scalarizes to s_load -> SGPR-operand v_fma, no per-FMA LDS reads);
//    activations round-trip an 8 KB per-thread-column LDS stage so k-loops
//    stay rolled (tiny I$, no scratch from runtime register indexing).

#define NLVL 16
#define TSZ   524288u
#define TMASK 524287u
#define PR1 2654435761u
#define PR2 805459861u

__device__ __constant__ int kResC[NLVL] = {16,24,36,54,81,121,182,273,410,615,922,1383,2075,3113,4670,7006};
constexpr int kRes[NLVL] = {16,24,36,54,81,121,182,273,410,615,922,1383,2075,3113,4670,7006};
constexpr bool kDense[NLVL] = {true,true,true,true,false,false,false,false,
                               false,false,false,false,false,false,false,false};

__device__ __forceinline__ void trilerp(const float2 f0, const float2 f1, const float2 f2, const float2 f3,
                                        const float2 f4, const float2 f5, const float2 f6, const float2 f7,
                                        float wx, float wy, float wz, float& a0, float& a1)
{
    const float ax = 1.f - wx, ay = 1.f - wy, az = 1.f - wz;
    const float g00 = ax * ay, g01 = ax * wy, g10 = wx * ay, g11 = wx * wy;
    float s0 = 0.f, s1 = 0.f, v;
    v = g00 * az; s0 = fmaf(v, f0.x, s0); s1 = fmaf(v, f0.y, s1);
    v = g00 * wz; s0 = fmaf(v, f1.x, s0); s1 = fmaf(v, f1.y, s1);
    v = g01 * az; s0 = fmaf(v, f2.x, s0); s1 = fmaf(v, f2.y, s1);
    v = g01 * wz; s0 = fmaf(v, f3.x, s0); s1 = fmaf(v, f3.y, s1);
    v = g10 * az; s0 = fmaf(v, f4.x, s0); s1 = fmaf(v, f4.y, s1);
    v = g10 * wz; s0 = fmaf(v, f5.x, s0); s1 = fmaf(v, f5.y, s1);
    v = g11 * az; s0 = fmaf(v, f6.x, s0); s1 = fmaf(v, f6.y, s1);
    v = g11 * wz; s0 = fmaf(v, f7.x, s0); s1 = fmaf(v, f7.y, s1);
    a0 = s0; a1 = s1;
}

__device__ __forceinline__ void hash_point(float px, float py, float pz, float res,
                                           const float2* __restrict__ tl,
                                           float& a0, float& a1)
{
    const float fx = px * res, fy = py * res, fz = pz * res;
    const float bx = floorf(fx), by = floorf(fy), bz = floorf(fz);
    const float wx = fx - bx, wy = fy - by, wz = fz - bz;
    const unsigned cx = (unsigned)bx, cy = (unsigned)by, cz = (unsigned)bz;
    const unsigned hy0 = cy * PR1, hy1 = hy0 + PR1;
    const unsigned hz0 = cz * PR2, hz1 = hz0 + PR2;
    const unsigned e00 = hy0 ^ hz0, e01 = hy0 ^ hz1, e10 = hy1 ^ hz0, e11 = hy1 ^ hz1;
    const unsigned x1 = cx + 1u;
    const float2 f0 = tl[(cx ^ e00) & TMASK];
    const float2 f1 = tl[(cx ^ e01) & TMASK];
    const float2 f2 = tl[(cx ^ e10) & TMASK];
    const float2 f3 = tl[(cx ^ e11) & TMASK];
    const float2 f4 = tl[(x1 ^ e00) & TMASK];
    const float2 f5 = tl[(x1 ^ e01) & TMASK];
    const float2 f6 = tl[(x1 ^ e10) & TMASK];
    const float2 f7 = tl[(x1 ^ e11) & TMASK];
    trilerp(f0,f1,f2,f3,f4,f5,f6,f7, wx,wy,wz, a0,a1);
}

template<int RES>
__device__ __forceinline__ void dense_point(float px, float py, float pz,
                                            const float2* __restrict__ tl,
                                            float& a0, float& a1)
{
    const float res = (float)RES;
    const float fx = px * res, fy = py * res, fz = pz * res;
    const float bx = floorf(fx), by = floorf(fy), bz = floorf(fz);
    const float wx = fx - bx, wy = fy - by, wz = fz - bz;
    const unsigned cx = (unsigned)bx, cy = (unsigned)by, cz = (unsigned)bz;
    const unsigned s = RES + 1u, s2 = s * s;
    const unsigned b = cx + cy * s + cz * s2;
    const float2 f0 = tl[b];
    const float2 f1 = tl[b + s2];
    const float2 f2 = tl[b + s];
    const float2 f3 = tl[b + s + s2];
    const float2 f4 = tl[b + 1u];
    const float2 f5 = tl[b + 1u + s2];
    const float2 f6 = tl[b + 1u + s];
    const float2 f7 = tl[b + 1u + s + s2];
    trilerp(f0,f1,f2,f3,f4,f5,f6,f7, wx,wy,wz, a0,a1);
}

// ---------------- dense levels 0-3: 1 pt/thread ----------------
__global__ __launch_bounds__(256)
void encode_dense(const float* __restrict__ x, const float* __restrict__ table,
                  float* __restrict__ hT, int n)
{
    const int i = blockIdx.x * 256 + threadIdx.x;
    if (i >= n) return;
    const float px = x[3*i+0], py = x[3*i+1], pz = x[3*i+2];
    const float2* tb = (const float2*)table;
    float a0, a1;
    dense_point<16>(px,py,pz, tb,              a0,a1);
    hT[i] = a0;                     hT[(size_t)n + i] = a1;
    dense_point<24>(px,py,pz, tb + TSZ,        a0,a1);
    hT[(size_t)2*n + i] = a0;       hT[(size_t)3*n + i] = a1;
    dense_point<36>(px,py,pz, tb + 2*(size_t)TSZ, a0,a1);
    hT[(size_t)4*n + i] = a0;       hT[(size_t)5*n + i] = a1;
    dense_point<54>(px,py,pz, tb + 3*(size_t)TSZ, a0,a1);
    hT[(size_t)6*n + i] = a0;       hT[(size_t)7*n + i] = a1;
}

// ---------------- hashed levels 4-15: level-major, 4 pts/thread ----------------
__global__ __launch_bounds__(256)
void encode_hash(const float* __restrict__ x, const float* __restrict__ table,
                 float* __restrict__ hT, int n, int chunks)
{
    const int bid  = blockIdx.x;
    const int pass = bid / chunks;             // uniform scalar div, once
    const int chunk = bid - pass * chunks;
    const int l = pass + 4;
    const float res = (float)kResC[l];
    const float2* __restrict__ tl = (const float2*)table + (size_t)l * TSZ;
    float* __restrict__ r0 = hT + (size_t)(2*l) * n;
    float* __restrict__ r1 = r0 + n;

    const int t  = threadIdx.x;
    const int i0 = (chunk << 10) + (t << 2);   // 1024 pts/block, 4/thread

    if (i0 + 3 < n) {
        // 3x float4 fully-coalesced x loads (12 floats = 4 points)
        const float4* __restrict__ xv = reinterpret_cast<const float4*>(x + (size_t)3 * i0);
        const float4 A = xv[0], B = xv[1], C = xv[2];
        const float px[4] = {A.x, A.w, B.z, C.y};
        const float py[4] = {A.y, B.x, B.w, C.z};
        const float pz[4] = {A.z, B.y, C.x, C.w};

        unsigned idx[4][8];
        float wx[4], wy[4], wz[4];
#pragma unroll
        for (int p = 0; p < 4; ++p) {
            const float fx = px[p]*res, fy = py[p]*res, fz = pz[p]*res;
            const float bx = floorf(fx), by = floorf(fy), bz = floorf(fz);
            wx[p] = fx - bx; wy[p] = fy - by; wz[p] = fz - bz;
            const unsigned cx = (unsigned)bx, cy = (unsigned)by, cz = (unsigned)bz;
            const unsigned hy0 = cy * PR1, hy1 = hy0 + PR1;
            const unsigned hz0 = cz * PR2, hz1 = hz0 + PR2;
            const unsigned e00 = hy0 ^ hz0, e01 = hy0 ^ hz1, e10 = hy1 ^ hz0, e11 = hy1 ^ hz1;
            const unsigned x1c = cx + 1u;
            idx[p][0] = (cx  ^ e00) & TMASK;  idx[p][1] = (cx  ^ e01) & TMASK;
            idx[p][2] = (cx  ^ e10) & TMASK;  idx[p][3] = (cx  ^ e11) & TMASK;
            idx[p][4] = (x1c ^ e00) & TMASK;  idx[p][5] = (x1c ^ e01) & TMASK;
            idx[p][6] = (x1c ^ e10) & TMASK;  idx[p][7] = (x1c ^ e11) & TMASK;
        }
        // all 32 gathers issued before any consumption (static indexing)
        float2 f[4][8];
#pragma unroll
        for (int p = 0; p < 4; ++p)
#pragma unroll
            for (int c = 0; c < 8; ++c) f[p][c] = tl[idx[p][c]];

        float o0[4], o1[4];
#pragma unroll
        for (int p = 0; p < 4; ++p)
            trilerp(f[p][0],f[p][1],f[p][2],f[p][3],f[p][4],f[p][5],f[p][6],f[p][7],
                    wx[p],wy[p],wz[p], o0[p],o1[p]);

        *reinterpret_cast<float4*>(r0 + i0) = make_float4(o0[0],o0[1],o0[2],o0[3]);
        *reinterpret_cast<float4*>(r1 + i0) = make_float4(o1[0],o1[1],o1[2],o1[3]);
    } else {
#pragma unroll
        for (int p = 0; p < 4; ++p) {
            const int i = i0 + p;
            if (i >= n) break;
            const float qx = x[3*i+0], qy = x[3*i+1], qz = x[3*i+2];
            float a0, a1;
            hash_point(qx,qy,qz, res, tl, a0,a1);
            r0[i] = a0; r1[i] = a1;
        }
    }
}

// ---------------- MLP: SGPR weights + per-thread-column LDS activation stage ----------------
__global__ __launch_bounds__(64)
void mlp_kernel(const float* __restrict__ hT,
                const float* __restrict__ W1,
                const float* __restrict__ W2,
                const float* __restrict__ W3,
                float* __restrict__ out, int n)
{
    __shared__ float hS[32 * 64];    // 8 KB, [k][tid]: per-thread column only
    const int t = threadIdx.x;
    const int i = blockIdx.x * 64 + t;
    if (i >= n) return;              // no barriers used anywhere

    // stage h straight into LDS (coalesced global reads)
#pragma unroll
    for (int f = 0; f < 32; ++f) hS[f * 64 + t] = hT[(size_t)f * n + i];

    // layer 1: 32 -> 64
    float h1[64];
#pragma unroll
    for (int j = 0; j < 64; ++j) h1[j] = 0.f;
    for (int k = 0; k < 32; ++k) {               // rolled: 1 ds_read + 16 s_load + 64 fma
        const float hk = hS[k * 64 + t];
        const float* __restrict__ Wr = W1 + k * 64;
#pragma unroll
        for (int q = 0; q < 16; ++q) {
            const float4 wv = *reinterpret_cast<const float4*>(Wr + 4*q);  // uniform -> s_load
            h1[4*q+0] = fmaf(hk, wv.x, h1[4*q+0]);
            h1[4*q+1] = fmaf(hk, wv.y, h1[4*q+1]);
            h1[4*q+2] = fmaf(hk, wv.z, h1[4*q+2]);
            h1[4*q+3] = fmaf(hk, wv.w, h1[4*q+3]);
        }
    }

    // layer 2: 64 -> 64 (relu applied while restaging h1 through LDS, 2 halves)
    float h2[64];
#pragma unroll
    for (int j = 0; j < 64; ++j) h2[j] = 0.f;
#pragma unroll
    for (int half = 0; half < 2; ++half) {
#pragma unroll
        for (int k = 0; k < 32; ++k) hS[k * 64 + t] = fmaxf(h1[half*32 + k], 0.f);
        for (int k = 0; k < 32; ++k) {
            const float hk = hS[k * 64 + t];
            const float* __restrict__ Wr = W2 + (half*32 + k) * 64;
#pragma unroll
            for (int q = 0; q < 16; ++q) {
                const float4 wv = *reinterpret_cast<const float4*>(Wr + 4*q);
                h2[4*q+0] = fmaf(hk, wv.x, h2[4*q+0]);
                h2[4*q+1] = fmaf(hk, wv.y, h2[4*q+1]);
                h2[4*q+2] = fmaf(hk, wv.z, h2[4*q+2]);
                h2[4*q+3] = fmaf(hk, wv.w, h2[4*q+3]);
            }
        }
    }

    // layer 3: 64 -> 16
    float h3[16];
#pragma unroll
    for (int j = 0; j < 16; ++j) h3[j] = 0.f;
#pragma unroll
    for (int half = 0; half < 2; ++half) {
#pragma unroll
        for (int k = 0; k < 32; ++k) hS[k * 64 + t] = fmaxf(h2[half*32 + k], 0.f);
        for (int k = 0; k < 32; ++k) {
            const float hk = hS[k * 64 + t];
            const float* __restrict__ Wr = W3 + (half*32 + k) * 16;
#pragma unroll
            for (int q = 0; q < 4; ++q) {
                const float4 wv = *reinterpret_cast<const float4*>(Wr + 4*q);
                h3[4*q+0] = fmaf(hk, wv.x, h3[4*q+0]);
                h3[4*q+1] = fmaf(hk, wv.y, h3[4*q+1]);
                h3[4*q+2] = fmaf(hk, wv.z, h3[4*q+2]);
                h3[4*q+3] = fmaf(hk, wv.w, h3[4*q+3]);
            }
        }
    }

    float4* __restrict__ o = reinterpret_cast<float4*>(out + (size_t)i * 16);
    o[0] = make_float4(h3[0],  h3[1],  h3[2],  h3[3]);
    o[1] = make_float4(h3[4],  h3[5],  h3[6],  h3[7]);
    o[2] = make_float4(h3[8],  h3[9],  h3[10], h3[11]);
    o[3] = make_float4(h3[12], h3[13], h3[14], h3[15]);
}

// ---------------- fallback: known-correct fused kernel ----------------
__global__ __launch_bounds__(256)
void ngp_fused_kernel(const float* __restrict__ x,
                      const float* __restrict__ table,
                      const float* __restrict__ W1,
                      const float* __restrict__ W2,
                      const float* __restrict__ W3,
                      float* __restrict__ out,
                      int n)
{
    __shared__ float hS[32 * 256];
    const int t = threadIdx.x;
    const int i = blockIdx.x * 256 + t;
    if (i >= n) return;
    const float px = x[3*i+0], py = x[3*i+1], pz = x[3*i+2];

    float h[32];
#pragma unroll
    for (int l = 0; l < NLVL; ++l) {
        float a0, a1;
        if (kDense[l]) {
            const int r = kRes[l];
            if (r == 16) dense_point<16>(px,py,pz,(const float2*)table+(size_t)l*TSZ,a0,a1);
            else if (r == 24) dense_point<24>(px,py,pz,(const float2*)table+(size_t)l*TSZ,a0,a1);
            else if (r == 36) dense_point<36>(px,py,pz,(const float2*)table+(size_t)l*TSZ,a0,a1);
            else dense_point<54>(px,py,pz,(const float2*)table+(size_t)l*TSZ,a0,a1);
        } else {
            hash_point(px,py,pz,(float)kRes[l],(const float2*)table+(size_t)l*TSZ,a0,a1);
        }
        h[2*l+0] = a0; h[2*l+1] = a1;
    }

#pragma unroll
    for (int k = 0; k < 32; ++k) hS[k * 256 + t] = h[k];
    float h1[64];
#pragma unroll
    for (int j = 0; j < 64; ++j) h1[j] = 0.f;
    for (int k = 0; k < 32; ++k) {
        const float hk = hS[k * 256 + t];
        const float* __restrict__ Wr = W1 + k * 64;
#pragma unroll
        for (int q = 0; q < 16; ++q) {
            const float4 wv = *reinterpret_cast<const float4*>(Wr + 4*q);
            h1[4*q+0]=fmaf(hk,wv.x,h1[4*q+0]); h1[4*q+1]=fmaf(hk,wv.y,h1[4*q+1]);
            h1[4*q+2]=fmaf(hk,wv.z,h1[4*q+2]); h1[4*q+3]=fmaf(hk,wv.w,h1[4*q+3]);
        }
    }
    float h2[64];
#pragma unroll
    for (int j = 0; j < 64; ++j) h2[j] = 0.f;
#pragma unroll
    for (int half = 0; half < 2; ++half) {
#pragma unroll
        for (int k = 0; k < 32; ++k) hS[k * 256 + t] = fmaxf(h1[half*32+k], 0.f);
        for (int k = 0; k < 32; ++k) {
            const float hk = hS[k * 256 + t];
            const float* __restrict__ Wr = W2 + (half*32+k) * 64;
#pragma unroll
            for (int q = 0; q < 16; ++q) {
                const float4 wv = *reinterpret_cast<const float4*>(Wr + 4*q);
                h2[4*q+0]=fmaf(hk,wv.x,h2[4*q+0]); h2[4*q+1]=fmaf(hk,wv.y,h2[4*q+1]);
                h2[4*q+2]=fmaf(hk,wv.z,h2[4*q+2]); h2[4*q+3]=fmaf(hk,wv.w,h2[4*q+3]);
            }
        }
    }
    float h3[16];
#pragma unroll
    for (int j = 0; j < 16; ++j) h3[j] = 0.f;
#pragma unroll
    for (int half = 0; half < 2; ++half) {
#pragma unroll
        for (int k = 0; k < 32; ++k) hS[k * 256 + t] = fmaxf(h2[half*32+k], 0.f);
        for (int k = 0; k < 32; ++k) {
            const float hk = hS[k * 256 + t];
            const float* __restrict__ Wr = W3 + (half*32+k) * 16;
#pragma unroll
            for (int q = 0; q < 4; ++q) {
                const float4 wv = *reinterpret_cast<const float4*>(Wr + 4*q);
                h3[4*q+0]=fmaf(hk,wv.x,h3[4*q+0]); h3[4*q+1]=fmaf(hk,wv.y,h3[4*q+1]);
                h3[4*q+2]=fmaf(hk,wv.z,h3[4*q+2]); h3[4*q+3]=fmaf(hk,wv.w,h3[4*q+3]);
            }
        }
    }
    float4* __restrict__ o = reinterpret_cast<float4*>(out + (size_t)i * 16);
    o[0] = make_float4(h3[0],h3[1],h3[2],h3[3]);
    o[1] = make_float4(h3[4],h3[5],h3[6],h3[7]);
    o[2] = make_float4(h3[8],h3[9],h3[10],h3[11]);
    o[3] = make_float4(h3[12],h3[13],h3[14],h3[15]);
}

extern "C" void kernel_launch(void* const* d_in, const int* in_sizes, int n_in,
                              void* d_out, int out_size, void* d_ws, size_t ws_size,
                              hipStream_t stream) {
    const float* x     = (const float*)d_in[0];
    const float* table = (const float*)d_in[1];
    const float* W1    = (const float*)d_in[2];
    const float* W2    = (const float*)d_in[3];
    const float* W3    = (const float*)d_in[4];
    float* out = (float*)d_out;

    const int n = in_sizes[0] / 3;
    const size_t need = (size_t)n * 32 * sizeof(float);

    if (ws_size >= need) {
        float* hT = (float*)d_ws;                         // [32][n] feature-major
        encode_dense<<<(n + 255) / 256, 256, 0, stream>>>(x, table, hT, n);
        const int chunks = (n + 1023) / 1024;             // 1024 pts per block
        encode_hash<<<12 * chunks, 256, 0, stream>>>(x, table, hT, n, chunks);
        mlp_kernel<<<(n + 63) / 64, 64, 0, stream>>>(hT, W1, W2, W3, out, n);
    } else {
        ngp_fused_kernel<<<(n + 255) / 256, 256, 0, stream>>>(x, table, W1, W2, W3, out, n);
    }
}